// Round 5
// baseline (1075.792 us; speedup 1.0000x reference)
//
#include <hip/hip_runtime.h>
#include <hip/hip_bf16.h>

#define HID 160
#define LM 768

__device__ __forceinline__ float leaky(float x) { return x > 0.0f ? x : 0.01f * x; }

// ---------------- CSR build ----------------
__global__ __launch_bounds__(256) void count_deg_kernel(const int* __restrict__ ei, int* __restrict__ deg, int E) {
    int e = blockIdx.x * 256 + threadIdx.x;
    if (e < E) atomicAdd(&deg[ei[E + e]], 1);
}

__global__ __launch_bounds__(1024) void scan_kernel(const int* __restrict__ deg, int* __restrict__ rowstart,
                                                    float* __restrict__ invd, int N) {
    __shared__ int wsum[16];
    __shared__ int carry_s;
    int t = threadIdx.x;
    int lane = t & 63;
    int w = t >> 6;
    if (t == 0) carry_s = 0;
    __syncthreads();
    for (int base = 0; base < N; base += 1024) {
        int i = base + t;
        int v = (i < N) ? deg[i] : 0;
        int x = v;
        #pragma unroll
        for (int off = 1; off < 64; off <<= 1) {
            int y = __shfl_up(x, off);
            x = (lane >= off) ? x + y : x;
        }
        if (lane == 63) wsum[w] = x;
        __syncthreads();
        int woff = 0;
        for (int k = 0; k < w; k++) woff += wsum[k];
        int excl = carry_s + woff + x - v;
        if (i < N) {
            rowstart[i] = excl;
            invd[i] = 1.0f / (float)(v > 0 ? v : 1);
        }
        __syncthreads();
        if (t == 1023) carry_s += woff + x;
        __syncthreads();
    }
}

__global__ __launch_bounds__(256) void fill_csr_kernel(const int* __restrict__ ei, const int* __restrict__ rowstart,
                                                       int* __restrict__ cursor, int* __restrict__ csr, int E) {
    int e = blockIdx.x * 256 + threadIdx.x;
    if (e < E) {
        int d = ei[E + e];
        int p = atomicAdd(&cursor[d], 1);
        csr[rowstart[d] + p] = ei[e];
    }
}

// ---------------- encoder: three 768->32 GEMMs (z picks input) ----------------
__global__ __launch_bounds__(256) void enc768_kernel(
    const float* __restrict__ des, const float* __restrict__ twt, const float* __restrict__ xx,
    const float* __restrict__ Wd, const float* __restrict__ Wt, const float* __restrict__ Wx,
    const float* __restrict__ bd, const float* __restrict__ bt, const float* __restrict__ bx,
    float* __restrict__ H0, int N) {
    __shared__ float As[128 * 65];
    __shared__ float Ws[64 * 32];
    int t = threadIdx.x;
    int z = blockIdx.z;
    const float* A = z == 0 ? des : (z == 1 ? twt : xx);
    const float* W = z == 0 ? Wd : (z == 1 ? Wt : Wx);
    const float* b = z == 0 ? bd : (z == 1 ? bt : bx);
    int colOff = 64 + 32 * z;
    int b0 = blockIdx.x * 128;
    int rg = t & 31, cg = t >> 5;
    float acc[4][4] = {};
    for (int kb = 0; kb < LM; kb += 64) {
        __syncthreads();
        #pragma unroll
        for (int i = 0; i < 8; i++) {
            int f = t + 256 * i;
            int row = f >> 4, kq = f & 15;
            int gr = b0 + row;
            float4 v = make_float4(0.f, 0.f, 0.f, 0.f);
            if (gr < N) v = *(const float4*)(A + (size_t)gr * LM + kb + 4 * kq);
            As[row * 65 + 4 * kq + 0] = v.x;
            As[row * 65 + 4 * kq + 1] = v.y;
            As[row * 65 + 4 * kq + 2] = v.z;
            As[row * 65 + 4 * kq + 3] = v.w;
        }
        #pragma unroll
        for (int i = 0; i < 2; i++) {
            int f = t + 256 * i;
            int row = f >> 3, q = f & 7;
            *(float4*)(Ws + row * 32 + 4 * q) = *(const float4*)(W + (size_t)(kb + row) * 32 + 4 * q);
        }
        __syncthreads();
        #pragma unroll 8
        for (int kk = 0; kk < 64; kk++) {
            float4 w = *(const float4*)(Ws + kk * 32 + 4 * cg);
            #pragma unroll
            for (int i = 0; i < 4; i++) {
                float a = As[(rg + 32 * i) * 65 + kk];
                acc[i][0] += a * w.x;
                acc[i][1] += a * w.y;
                acc[i][2] += a * w.z;
                acc[i][3] += a * w.w;
            }
        }
    }
    float b0v = b[4 * cg + 0], b1v = b[4 * cg + 1], b2v = b[4 * cg + 2], b3v = b[4 * cg + 3];
    #pragma unroll
    for (int i = 0; i < 4; i++) {
        int gr = b0 + rg + 32 * i;
        if (gr < N) {
            float4 o;
            o.x = leaky(acc[i][0] + b0v);
            o.y = leaky(acc[i][1] + b1v);
            o.z = leaky(acc[i][2] + b2v);
            o.w = leaky(acc[i][3] + b3v);
            *(float4*)(H0 + (size_t)gr * HID + colOff + 4 * cg) = o;
        }
    }
}

// ---------------- encoder: num_prop (6->32) + num_category (11->32) ----------------
__global__ __launch_bounds__(256) void enc_small_kernel(
    const float* __restrict__ npr, const float* __restrict__ ncat,
    const float* __restrict__ Wnp, const float* __restrict__ bnp,
    const float* __restrict__ Wnc, const float* __restrict__ bnc,
    float* __restrict__ H0, int N) {
    __shared__ float sWnp[192], sbnp[32], sWnc[352], sbnc[32];
    int t = threadIdx.x;
    if (t < 192) sWnp[t] = Wnp[t];
    for (int i = t; i < 352; i += 256) sWnc[i] = Wnc[i];
    if (t < 32) { sbnp[t] = bnp[t]; sbnc[t] = bnc[t]; }
    __syncthreads();
    int i = blockIdx.x * 256 + t;
    if (i >= N) return;
    float a[11];
    #pragma unroll
    for (int j = 0; j < 6; j++) a[j] = npr[(size_t)i * 6 + j];
    float o[32];
    #pragma unroll
    for (int c = 0; c < 32; c++) {
        float s = sbnp[c];
        #pragma unroll
        for (int j = 0; j < 6; j++) s += a[j] * sWnp[j * 32 + c];
        o[c] = leaky(s);
    }
    #pragma unroll
    for (int q = 0; q < 8; q++)
        *(float4*)(H0 + (size_t)i * HID + 4 * q) = make_float4(o[4 * q], o[4 * q + 1], o[4 * q + 2], o[4 * q + 3]);
    #pragma unroll
    for (int j = 0; j < 11; j++) a[j] = ncat[(size_t)i * 11 + j];
    #pragma unroll
    for (int c = 0; c < 32; c++) {
        float s = sbnc[c];
        #pragma unroll
        for (int j = 0; j < 11; j++) s += a[j] * sWnc[j * 32 + c];
        o[c] = leaky(s);
    }
    #pragma unroll
    for (int q = 0; q < 8; q++)
        *(float4*)(H0 + (size_t)i * HID + 32 + 4 * q) = make_float4(o[4 * q], o[4 * q + 1], o[4 * q + 2], o[4 * q + 3]);
}

// ---------------- 160x160 GEMM (optionally dual-source, optional leaky) ----------------
// C[N,160] = act(A1 @ W1 (+ A2 @ W2) + bias). In-place C==A1 or C==A2 is safe (row-partitioned).
template <bool DUAL, bool ACT>
__global__ __launch_bounds__(256) void gemm160_kernel(
    const float* __restrict__ A1, const float* __restrict__ W1,
    const float* __restrict__ A2, const float* __restrict__ W2,
    const float* __restrict__ bias, float* __restrict__ C, int N) {
    __shared__ float As[64 * 33];
    __shared__ float Ws[32 * 160];
    int t = threadIdx.x;
    int b0 = blockIdx.x * 64;
    int rg = t & 15, cg = t >> 4;
    float acc[4][10] = {};
    const int NC = DUAL ? 10 : 5;
    for (int c = 0; c < NC; c++) {
        const float* A = (c < 5) ? A1 : A2;
        const float* W = (c < 5) ? W1 : W2;
        int kb = 32 * (c % 5);
        __syncthreads();
        #pragma unroll
        for (int i = 0; i < 2; i++) {
            int f = t + 256 * i;
            int row = f >> 3, kq = f & 7;
            int gr = b0 + row;
            float4 v = make_float4(0.f, 0.f, 0.f, 0.f);
            if (gr < N) v = *(const float4*)(A + (size_t)gr * HID + kb + 4 * kq);
            As[row * 33 + 4 * kq + 0] = v.x;
            As[row * 33 + 4 * kq + 1] = v.y;
            As[row * 33 + 4 * kq + 2] = v.z;
            As[row * 33 + 4 * kq + 3] = v.w;
        }
        #pragma unroll
        for (int i = 0; i < 5; i++) {
            int f = t + 256 * i;
            int row = f / 40, q = f % 40;
            *(float4*)(Ws + row * 160 + 4 * q) = *(const float4*)(W + (size_t)(kb + row) * 160 + 4 * q);
        }
        __syncthreads();
        #pragma unroll 4
        for (int kk = 0; kk < 32; kk++) {
            float a[4];
            #pragma unroll
            for (int i = 0; i < 4; i++) a[i] = As[(rg + 16 * i) * 33 + kk];
            const float2* wp = (const float2*)(Ws + kk * 160 + 10 * cg);
            #pragma unroll
            for (int j = 0; j < 5; j++) {
                float2 w = wp[j];
                #pragma unroll
                for (int i = 0; i < 4; i++) {
                    acc[i][2 * j + 0] += a[i] * w.x;
                    acc[i][2 * j + 1] += a[i] * w.y;
                }
            }
        }
    }
    float bv[10];
    #pragma unroll
    for (int j = 0; j < 10; j++) bv[j] = bias[10 * cg + j];
    #pragma unroll
    for (int i = 0; i < 4; i++) {
        int gr = b0 + rg + 16 * i;
        if (gr < N) {
            float* Cr = C + (size_t)gr * HID + 10 * cg;
            #pragma unroll
            for (int j = 0; j < 5; j++) {
                float vx = acc[i][2 * j + 0] + bv[2 * j + 0];
                float vy = acc[i][2 * j + 1] + bv[2 * j + 1];
                if (ACT) { vx = leaky(vx); vy = leaky(vy); }
                *(float2*)(Cr + 2 * j) = make_float2(vx, vy);
            }
        }
    }
}

// ---------------- mean aggregation over CSR: one wave per node ----------------
__global__ __launch_bounds__(256) void agg_kernel(const float* __restrict__ H,
                                                  const int* __restrict__ rowstart, const int* __restrict__ deg,
                                                  const int* __restrict__ csr, const float* __restrict__ invd,
                                                  float* __restrict__ M, int N) {
    int wid = (blockIdx.x * 256 + threadIdx.x) >> 6;
    int lane = threadIdx.x & 63;
    if (wid >= N) return;
    int rs = rowstart[wid];
    int d = deg[wid];
    float inv = invd[wid];
    if (lane < 40) {
        float4 acc = make_float4(0.f, 0.f, 0.f, 0.f);
        const float4* Hv = (const float4*)H;
        for (int j = 0; j < d; j++) {
            int s = csr[rs + j];
            float4 v = Hv[(size_t)s * 40 + lane];
            acc.x += v.x; acc.y += v.y; acc.z += v.z; acc.w += v.w;
        }
        float4 o = make_float4(acc.x * inv, acc.y * inv, acc.z * inv, acc.w * inv);
        ((float4*)M)[(size_t)wid * 40 + lane] = o;
    }
}

// ---------------- output head: out = em @ W_o2 + b_o2 ----------------
__global__ __launch_bounds__(256) void out_head_kernel(const float* __restrict__ em,
                                                       const float* __restrict__ Wo2, const float* __restrict__ bo2,
                                                       float* __restrict__ out, int N) {
    __shared__ float sW[320];
    __shared__ float sb[2];
    int t = threadIdx.x;
    for (int i = t; i < 320; i += 256) sW[i] = Wo2[i];
    if (t < 2) sb[t] = bo2[t];
    __syncthreads();
    int i = blockIdx.x * 256 + t;
    if (i >= N) return;
    const float4* er = (const float4*)em + (size_t)i * 40;
    float ax = sb[0], ay = sb[1];
    #pragma unroll 4
    for (int q = 0; q < 40; q++) {
        float4 v = er[q];
        int k = 8 * q;
        ax += v.x * sW[k + 0] + v.y * sW[k + 2] + v.z * sW[k + 4] + v.w * sW[k + 6];
        ay += v.x * sW[k + 1] + v.y * sW[k + 3] + v.z * sW[k + 5] + v.w * sW[k + 7];
    }
    out[2 * i + 0] = ax;
    out[2 * i + 1] = ay;
}

extern "C" void kernel_launch(void* const* d_in, const int* in_sizes, int n_in,
                              void* d_out, int out_size, void* d_ws, size_t ws_size,
                              hipStream_t stream) {
    const float* x        = (const float*)d_in[0];
    const int*   ei       = (const int*)d_in[1];
    const float* num_prop = (const float*)d_in[2];
    const float* num_cat  = (const float*)d_in[3];
    const float* des      = (const float*)d_in[4];
    const float* twt      = (const float*)d_in[5];
    const float* W_des = (const float*)d_in[6],  *b_des = (const float*)d_in[7];
    const float* W_tw  = (const float*)d_in[8],  *b_tw  = (const float*)d_in[9];
    const float* W_txt = (const float*)d_in[10], *b_txt = (const float*)d_in[11];
    const float* W_np  = (const float*)d_in[12], *b_np  = (const float*)d_in[13];
    const float* W_nc  = (const float*)d_in[14], *b_nc  = (const float*)d_in[15];
    const float* W_in  = (const float*)d_in[16], *b_in  = (const float*)d_in[17];
    const float* W_l   = (const float*)d_in[18], *b_l   = (const float*)d_in[19];
    const float* W_r   = (const float*)d_in[20];
    const float* W_o1  = (const float*)d_in[21], *b_o1  = (const float*)d_in[22];
    const float* W_o2  = (const float*)d_in[23], *b_o2  = (const float*)d_in[24];

    const int N = in_sizes[0] / LM;
    const int E = in_sizes[1] / 2;

    float* bufA = (float*)d_ws;
    float* bufB = bufA + (size_t)N * HID;
    int* deg      = (int*)(bufB + (size_t)N * HID);
    int* cursor   = deg + N;
    int* rowstart = cursor + N;
    float* invd   = (float*)(rowstart + N);
    int* csr      = (int*)(invd + N);

    float* out_ptr = (float*)d_out;            // [N,2]
    float* em_ptr  = out_ptr + (size_t)N * 2;  // [N,160]

    // CSR build (reused by both convs)
    hipMemsetAsync(deg, 0, sizeof(int) * (size_t)(2 * N), stream);  // deg + cursor
    count_deg_kernel<<<(E + 255) / 256, 256, 0, stream>>>(ei, deg, E);
    scan_kernel<<<1, 1024, 0, stream>>>(deg, rowstart, invd, N);
    fill_csr_kernel<<<(E + 255) / 256, 256, 0, stream>>>(ei, rowstart, cursor, csr, E);

    // feature encoders -> h0 in bufA
    dim3 egrid((N + 127) / 128, 1, 3);
    enc768_kernel<<<egrid, 256, 0, stream>>>(des, twt, x, W_des, W_tw, W_txt, b_des, b_tw, b_txt, bufA, N);
    enc_small_kernel<<<(N + 255) / 256, 256, 0, stream>>>(num_prop, num_cat, W_np, b_np, W_nc, b_nc, bufA, N);

    int g64 = (N + 63) / 64;
    // h1 = leaky(h0 @ W_in + b_in)  : bufA -> bufB
    gemm160_kernel<false, true><<<g64, 256, 0, stream>>>(bufA, W_in, nullptr, nullptr, b_in, bufB, N);
    // mean1 = agg(h1)               : bufB -> bufA
    agg_kernel<<<(N + 3) / 4, 256, 0, stream>>>(bufB, rowstart, deg, csr, invd, bufA, N);
    // h2 = mean1 @ W_l + h1 @ W_r + b_l : (bufA,bufB) -> bufA (in-place safe)
    gemm160_kernel<true, false><<<g64, 256, 0, stream>>>(bufA, W_l, bufB, W_r, b_l, bufA, N);
    // mean2 = agg(h2)               : bufA -> bufB
    agg_kernel<<<(N + 3) / 4, 256, 0, stream>>>(bufA, rowstart, deg, csr, invd, bufB, N);
    // h3 = mean2 @ W_l + h2 @ W_r + b_l : (bufB,bufA) -> bufB
    gemm160_kernel<true, false><<<g64, 256, 0, stream>>>(bufB, W_l, bufA, W_r, b_l, bufB, N);
    // em = leaky(h3 @ W_o1 + b_o1)  : bufB -> em (d_out)
    gemm160_kernel<false, true><<<g64, 256, 0, stream>>>(bufB, W_o1, nullptr, nullptr, b_o1, em_ptr, N);
    // out = em @ W_o2 + b_o2
    out_head_kernel<<<(N + 255) / 256, 256, 0, stream>>>(em_ptr, W_o2, b_o2, out_ptr, N);
}

// Round 7
// 1018.927 us; speedup vs baseline: 1.0558x; 1.0558x over previous
//
#include <hip/hip_runtime.h>
#include <hip/hip_bf16.h>

#define HID 160
#define LM 768

__device__ __forceinline__ float leaky(float x) { return x > 0.0f ? x : 0.01f * x; }

// ---------------- CSR build ----------------
__global__ __launch_bounds__(256) void count_deg_kernel(const int* __restrict__ ei, int* __restrict__ deg, int E) {
    int e = blockIdx.x * 256 + threadIdx.x;
    if (e < E) atomicAdd(&deg[ei[E + e]], 1);
}

__global__ __launch_bounds__(1024) void scan_kernel(const int* __restrict__ deg, int* __restrict__ rowstart,
                                                    float* __restrict__ invd, int N) {
    __shared__ int wsum[16];
    __shared__ int carry_s;
    int t = threadIdx.x;
    int lane = t & 63;
    int w = t >> 6;
    if (t == 0) carry_s = 0;
    __syncthreads();
    for (int base = 0; base < N; base += 1024) {
        int i = base + t;
        int v = (i < N) ? deg[i] : 0;
        int x = v;
        #pragma unroll
        for (int off = 1; off < 64; off <<= 1) {
            int y = __shfl_up(x, off);
            x = (lane >= off) ? x + y : x;
        }
        if (lane == 63) wsum[w] = x;
        __syncthreads();
        int woff = 0;
        for (int k = 0; k < w; k++) woff += wsum[k];
        int excl = carry_s + woff + x - v;
        if (i < N) {
            rowstart[i] = excl;
            invd[i] = 1.0f / (float)(v > 0 ? v : 1);
        }
        __syncthreads();
        if (t == 1023) carry_s += woff + x;
        __syncthreads();
    }
}

__global__ __launch_bounds__(256) void fill_csr_kernel(const int* __restrict__ ei, const int* __restrict__ rowstart,
                                                       int* __restrict__ cursor, int* __restrict__ csr, int E) {
    int e = blockIdx.x * 256 + threadIdx.x;
    if (e < E) {
        int d = ei[E + e];
        int p = atomicAdd(&cursor[d], 1);
        csr[rowstart[d] + p] = ei[e];
    }
}

// ---------------- encoder: three 768->32 GEMMs (z picks input) ----------------
// v2: TM=64 tile, K-vectorized float4 LDS reads (As pad 68, Ws pad 36),
// 2 rows x 4 cols per thread -> 32 FMA per 6 LDS b128 instrs.
// LDS = 26.6 KB/block -> 6 blocks/CU resident.
#define ETM 64
__global__ __launch_bounds__(256, 4) void enc768_kernel(
    const float* __restrict__ des, const float* __restrict__ twt, const float* __restrict__ xx,
    const float* __restrict__ Wd, const float* __restrict__ Wt, const float* __restrict__ Wx,
    const float* __restrict__ bd, const float* __restrict__ bt, const float* __restrict__ bx,
    float* __restrict__ H0, int N) {
    __shared__ float As[ETM * 68];
    __shared__ float Ws[64 * 36];
    int t = threadIdx.x;
    int z = blockIdx.z;
    const float* A = z == 0 ? des : (z == 1 ? twt : xx);
    const float* W = z == 0 ? Wd : (z == 1 ? Wt : Wx);
    const float* b = z == 0 ? bd : (z == 1 ? bt : bx);
    int colOff = 64 + 32 * z;
    int b0 = blockIdx.x * ETM;
    int rg = t & 31, cg = t >> 5;  // rows {rg, rg+32}, cols 4cg..4cg+3
    float acc0[4] = {};
    float acc1[4] = {};
    for (int kb = 0; kb < LM; kb += 64) {
        __syncthreads();
        // stage A: 64 rows x 64 k = 1024 float4; 4 per thread
        #pragma unroll
        for (int i = 0; i < 4; i++) {
            int f = t + 256 * i;
            int row = f >> 4, kq = f & 15;
            int gr = b0 + row;
            float4 v = make_float4(0.f, 0.f, 0.f, 0.f);
            if (gr < N) v = *(const float4*)(A + (size_t)gr * LM + kb + 4 * kq);
            *(float4*)(&As[row * 68 + 4 * kq]) = v;
        }
        // stage W: 64 x 32 = 512 float4; 2 per thread
        #pragma unroll
        for (int i = 0; i < 2; i++) {
            int f = t + 256 * i;
            int row = f >> 3, q = f & 7;
            *(float4*)(&Ws[row * 36 + 4 * q]) = *(const float4*)(W + (size_t)(kb + row) * 32 + 4 * q);
        }
        __syncthreads();
        #pragma unroll
        for (int k4 = 0; k4 < 16; k4++) {
            float4 a0 = *(const float4*)(&As[rg * 68 + 4 * k4]);
            float4 a1 = *(const float4*)(&As[(rg + 32) * 68 + 4 * k4]);
            float a0v[4] = {a0.x, a0.y, a0.z, a0.w};
            float a1v[4] = {a1.x, a1.y, a1.z, a1.w};
            #pragma unroll
            for (int j = 0; j < 4; j++) {
                float4 w = *(const float4*)(&Ws[(4 * k4 + j) * 36 + 4 * cg]);
                acc0[0] += a0v[j] * w.x; acc0[1] += a0v[j] * w.y;
                acc0[2] += a0v[j] * w.z; acc0[3] += a0v[j] * w.w;
                acc1[0] += a1v[j] * w.x; acc1[1] += a1v[j] * w.y;
                acc1[2] += a1v[j] * w.z; acc1[3] += a1v[j] * w.w;
            }
        }
    }
    float4 bv = *(const float4*)(b + 4 * cg);
    int gr0 = b0 + rg;
    if (gr0 < N) {
        float4 o;
        o.x = leaky(acc0[0] + bv.x); o.y = leaky(acc0[1] + bv.y);
        o.z = leaky(acc0[2] + bv.z); o.w = leaky(acc0[3] + bv.w);
        *(float4*)(H0 + (size_t)gr0 * HID + colOff + 4 * cg) = o;
    }
    int gr1 = b0 + rg + 32;
    if (gr1 < N) {
        float4 o;
        o.x = leaky(acc1[0] + bv.x); o.y = leaky(acc1[1] + bv.y);
        o.z = leaky(acc1[2] + bv.z); o.w = leaky(acc1[3] + bv.w);
        *(float4*)(H0 + (size_t)gr1 * HID + colOff + 4 * cg) = o;
    }
}

// ---------------- encoder: num_prop (6->32) + num_category (11->32) ----------------
__global__ __launch_bounds__(256) void enc_small_kernel(
    const float* __restrict__ npr, const float* __restrict__ ncat,
    const float* __restrict__ Wnp, const float* __restrict__ bnp,
    const float* __restrict__ Wnc, const float* __restrict__ bnc,
    float* __restrict__ H0, int N) {
    __shared__ float sWnp[192], sbnp[32], sWnc[352], sbnc[32];
    int t = threadIdx.x;
    if (t < 192) sWnp[t] = Wnp[t];
    for (int i = t; i < 352; i += 256) sWnc[i] = Wnc[i];
    if (t < 32) { sbnp[t] = bnp[t]; sbnc[t] = bnc[t]; }
    __syncthreads();
    int i = blockIdx.x * 256 + t;
    if (i >= N) return;
    float a[11];
    #pragma unroll
    for (int j = 0; j < 6; j++) a[j] = npr[(size_t)i * 6 + j];
    float o[32];
    #pragma unroll
    for (int c = 0; c < 32; c++) {
        float s = sbnp[c];
        #pragma unroll
        for (int j = 0; j < 6; j++) s += a[j] * sWnp[j * 32 + c];
        o[c] = leaky(s);
    }
    #pragma unroll
    for (int q = 0; q < 8; q++)
        *(float4*)(H0 + (size_t)i * HID + 4 * q) = make_float4(o[4 * q], o[4 * q + 1], o[4 * q + 2], o[4 * q + 3]);
    #pragma unroll
    for (int j = 0; j < 11; j++) a[j] = ncat[(size_t)i * 11 + j];
    #pragma unroll
    for (int c = 0; c < 32; c++) {
        float s = sbnc[c];
        #pragma unroll
        for (int j = 0; j < 11; j++) s += a[j] * sWnc[j * 32 + c];
        o[c] = leaky(s);
    }
    #pragma unroll
    for (int q = 0; q < 8; q++)
        *(float4*)(H0 + (size_t)i * HID + 32 + 4 * q) = make_float4(o[4 * q], o[4 * q + 1], o[4 * q + 2], o[4 * q + 3]);
}

// ---------------- 160x160 GEMM (optionally dual-source, optional leaky) ----------------
// C[N,160] = act(A1 @ W1 (+ A2 @ W2) + bias). In-place C==A1 or C==A2 is safe (row-partitioned).
template <bool DUAL, bool ACT>
__global__ __launch_bounds__(256) void gemm160_kernel(
    const float* __restrict__ A1, const float* __restrict__ W1,
    const float* __restrict__ A2, const float* __restrict__ W2,
    const float* __restrict__ bias, float* __restrict__ C, int N) {
    __shared__ float As[64 * 33];
    __shared__ float Ws[32 * 160];
    int t = threadIdx.x;
    int b0 = blockIdx.x * 64;
    int rg = t & 15, cg = t >> 4;
    float acc[4][10] = {};
    const int NC = DUAL ? 10 : 5;
    for (int c = 0; c < NC; c++) {
        const float* A = (c < 5) ? A1 : A2;
        const float* W = (c < 5) ? W1 : W2;
        int kb = 32 * (c % 5);
        __syncthreads();
        #pragma unroll
        for (int i = 0; i < 2; i++) {
            int f = t + 256 * i;
            int row = f >> 3, kq = f & 7;
            int gr = b0 + row;
            float4 v = make_float4(0.f, 0.f, 0.f, 0.f);
            if (gr < N) v = *(const float4*)(A + (size_t)gr * HID + kb + 4 * kq);
            As[row * 33 + 4 * kq + 0] = v.x;
            As[row * 33 + 4 * kq + 1] = v.y;
            As[row * 33 + 4 * kq + 2] = v.z;
            As[row * 33 + 4 * kq + 3] = v.w;
        }
        #pragma unroll
        for (int i = 0; i < 5; i++) {
            int f = t + 256 * i;
            int row = f / 40, q = f % 40;
            *(float4*)(Ws + row * 160 + 4 * q) = *(const float4*)(W + (size_t)(kb + row) * 160 + 4 * q);
        }
        __syncthreads();
        #pragma unroll 4
        for (int kk = 0; kk < 32; kk++) {
            float a[4];
            #pragma unroll
            for (int i = 0; i < 4; i++) a[i] = As[(rg + 16 * i) * 33 + kk];
            const float2* wp = (const float2*)(Ws + kk * 160 + 10 * cg);
            #pragma unroll
            for (int j = 0; j < 5; j++) {
                float2 w = wp[j];
                #pragma unroll
                for (int i = 0; i < 4; i++) {
                    acc[i][2 * j + 0] += a[i] * w.x;
                    acc[i][2 * j + 1] += a[i] * w.y;
                }
            }
        }
    }
    float bv[10];
    #pragma unroll
    for (int j = 0; j < 10; j++) bv[j] = bias[10 * cg + j];
    #pragma unroll
    for (int i = 0; i < 4; i++) {
        int gr = b0 + rg + 16 * i;
        if (gr < N) {
            float* Cr = C + (size_t)gr * HID + 10 * cg;
            #pragma unroll
            for (int j = 0; j < 5; j++) {
                float vx = acc[i][2 * j + 0] + bv[2 * j + 0];
                float vy = acc[i][2 * j + 1] + bv[2 * j + 1];
                if (ACT) { vx = leaky(vx); vy = leaky(vy); }
                *(float2*)(Cr + 2 * j) = make_float2(vx, vy);
            }
        }
    }
}

// ---------------- mean aggregation over CSR: one wave per node ----------------
__global__ __launch_bounds__(256) void agg_kernel(const float* __restrict__ H,
                                                  const int* __restrict__ rowstart, const int* __restrict__ deg,
                                                  const int* __restrict__ csr, const float* __restrict__ invd,
                                                  float* __restrict__ M, int N) {
    int wid = (blockIdx.x * 256 + threadIdx.x) >> 6;
    int lane = threadIdx.x & 63;
    if (wid >= N) return;
    int rs = rowstart[wid];
    int d = deg[wid];
    float inv = invd[wid];
    if (lane < 40) {
        float4 acc = make_float4(0.f, 0.f, 0.f, 0.f);
        const float4* Hv = (const float4*)H;
        for (int j = 0; j < d; j++) {
            int s = csr[rs + j];
            float4 v = Hv[(size_t)s * 40 + lane];
            acc.x += v.x; acc.y += v.y; acc.z += v.z; acc.w += v.w;
        }
        float4 o = make_float4(acc.x * inv, acc.y * inv, acc.z * inv, acc.w * inv);
        ((float4*)M)[(size_t)wid * 40 + lane] = o;
    }
}

// ---------------- output head: out = em @ W_o2 + b_o2 ----------------
__global__ __launch_bounds__(256) void out_head_kernel(const float* __restrict__ em,
                                                       const float* __restrict__ Wo2, const float* __restrict__ bo2,
                                                       float* __restrict__ out, int N) {
    __shared__ float sW[320];
    __shared__ float sb[2];
    int t = threadIdx.x;
    for (int i = t; i < 320; i += 256) sW[i] = Wo2[i];
    if (t < 2) sb[t] = bo2[t];
    __syncthreads();
    int i = blockIdx.x * 256 + t;
    if (i >= N) return;
    const float4* er = (const float4*)em + (size_t)i * 40;
    float ax = sb[0], ay = sb[1];
    #pragma unroll 4
    for (int q = 0; q < 40; q++) {
        float4 v = er[q];
        int k = 8 * q;
        ax += v.x * sW[k + 0] + v.y * sW[k + 2] + v.z * sW[k + 4] + v.w * sW[k + 6];
        ay += v.x * sW[k + 1] + v.y * sW[k + 3] + v.z * sW[k + 5] + v.w * sW[k + 7];
    }
    out[2 * i + 0] = ax;
    out[2 * i + 1] = ay;
}

extern "C" void kernel_launch(void* const* d_in, const int* in_sizes, int n_in,
                              void* d_out, int out_size, void* d_ws, size_t ws_size,
                              hipStream_t stream) {
    const float* x        = (const float*)d_in[0];
    const int*   ei       = (const int*)d_in[1];
    const float* num_prop = (const float*)d_in[2];
    const float* num_cat  = (const float*)d_in[3];
    const float* des      = (const float*)d_in[4];
    const float* twt      = (const float*)d_in[5];
    const float* W_des = (const float*)d_in[6],  *b_des = (const float*)d_in[7];
    const float* W_tw  = (const float*)d_in[8],  *b_tw  = (const float*)d_in[9];
    const float* W_txt = (const float*)d_in[10], *b_txt = (const float*)d_in[11];
    const float* W_np  = (const float*)d_in[12], *b_np  = (const float*)d_in[13];
    const float* W_nc  = (const float*)d_in[14], *b_nc  = (const float*)d_in[15];
    const float* W_in  = (const float*)d_in[16], *b_in  = (const float*)d_in[17];
    const float* W_l   = (const float*)d_in[18], *b_l   = (const float*)d_in[19];
    const float* W_r   = (const float*)d_in[20];
    const float* W_o1  = (const float*)d_in[21], *b_o1  = (const float*)d_in[22];
    const float* W_o2  = (const float*)d_in[23], *b_o2  = (const float*)d_in[24];

    const int N = in_sizes[0] / LM;
    const int E = in_sizes[1] / 2;

    float* bufA = (float*)d_ws;
    float* bufB = bufA + (size_t)N * HID;
    int* deg      = (int*)(bufB + (size_t)N * HID);
    int* cursor   = deg + N;
    int* rowstart = cursor + N;
    float* invd   = (float*)(rowstart + N);
    int* csr      = (int*)(invd + N);

    float* out_ptr = (float*)d_out;            // [N,2]
    float* em_ptr  = out_ptr + (size_t)N * 2;  // [N,160]

    // CSR build (reused by both convs)
    hipMemsetAsync(deg, 0, sizeof(int) * (size_t)(2 * N), stream);  // deg + cursor
    count_deg_kernel<<<(E + 255) / 256, 256, 0, stream>>>(ei, deg, E);
    scan_kernel<<<1, 1024, 0, stream>>>(deg, rowstart, invd, N);
    fill_csr_kernel<<<(E + 255) / 256, 256, 0, stream>>>(ei, rowstart, cursor, csr, E);

    // feature encoders -> h0 in bufA
    dim3 egrid((N + ETM - 1) / ETM, 1, 3);
    enc768_kernel<<<egrid, 256, 0, stream>>>(des, twt, x, W_des, W_tw, W_txt, b_des, b_tw, b_txt, bufA, N);
    enc_small_kernel<<<(N + 255) / 256, 256, 0, stream>>>(num_prop, num_cat, W_np, b_np, W_nc, b_nc, bufA, N);

    int g64 = (N + 63) / 64;
    // h1 = leaky(h0 @ W_in + b_in)  : bufA -> bufB
    gemm160_kernel<false, true><<<g64, 256, 0, stream>>>(bufA, W_in, nullptr, nullptr, b_in, bufB, N);
    // mean1 = agg(h1)               : bufB -> bufA
    agg_kernel<<<(N + 3) / 4, 256, 0, stream>>>(bufB, rowstart, deg, csr, invd, bufA, N);
    // h2 = mean1 @ W_l + h1 @ W_r + b_l : (bufA,bufB) -> bufA (in-place safe)
    gemm160_kernel<true, false><<<g64, 256, 0, stream>>>(bufA, W_l, bufB, W_r, b_l, bufA, N);
    // mean2 = agg(h2)               : bufA -> bufB
    agg_kernel<<<(N + 3) / 4, 256, 0, stream>>>(bufA, rowstart, deg, csr, invd, bufB, N);
    // h3 = mean2 @ W_l + h2 @ W_r + b_l : (bufB,bufA) -> bufB
    gemm160_kernel<true, false><<<g64, 256, 0, stream>>>(bufB, W_l, bufA, W_r, b_l, bufB, N);
    // em = leaky(h3 @ W_o1 + b_o1)  : bufB -> em (d_out)
    gemm160_kernel<false, true><<<g64, 256, 0, stream>>>(bufB, W_o1, nullptr, nullptr, b_o1, em_ptr, N);
    // out = em @ W_o2 + b_o2
    out_head_kernel<<<(N + 255) / 256, 256, 0, stream>>>(em_ptr, W_o2, b_o2, out_ptr, N);
}